// Round 1
// baseline (1430.902 us; speedup 1.0000x reference)
//
#include <hip/hip_runtime.h>
#include <hip/hip_bf16.h>

typedef short short8 __attribute__((ext_vector_type(8)));
typedef float floatx4 __attribute__((ext_vector_type(4)));

constexpr int Bc = 64, Lc = 2688, Cc = 256, Wc = 42, Sc = 21, Hc = 8, HDc = 32;
constexpr int Mrows = Bc * Lc;          // 172032
constexpr float QSCALE = 0.17677669529663689f;  // 32^-0.5

// ---------------- weight transpose + cast: w (K x N) fp32 -> wT (N x K) bf16 ----------------
__global__ __launch_bounds__(256) void transpose_cast_k(const float* __restrict__ w,
                                                        __hip_bfloat16* __restrict__ o,
                                                        int K, int N) {
  int idx = blockIdx.x * 256 + threadIdx.x;
  if (idx >= K * N) return;
  int n = idx / K, k = idx - n * K;
  o[idx] = __float2bfloat16(w[(size_t)k * N + n]);
}

// ---------------- LayerNorm (+ optional cyclic shift on source row) -> bf16 ----------------
// out[b, i, :] = LN(x[b, (i + roll) % L, :]) * g + b
__global__ __launch_bounds__(256) void ln_k(const float* __restrict__ x, const float* __restrict__ g,
                                            const float* __restrict__ bta, __hip_bfloat16* __restrict__ out,
                                            int roll) {
  int row = blockIdx.x;                 // output row in [0, B*L)
  int bb = row / Lc, rl = row - bb * Lc;
  int sl = rl + roll; if (sl >= Lc) sl -= Lc;
  const float* xr = x + ((size_t)bb * Lc + sl) * Cc;
  int t = threadIdx.x;
  float v = xr[t];
  float s = v;
#pragma unroll
  for (int o = 1; o < 64; o <<= 1) s += __shfl_xor(s, o, 64);
  __shared__ float red[4];
  int wv = t >> 6;
  if ((t & 63) == 0) red[wv] = s;
  __syncthreads();
  float mean = (red[0] + red[1] + red[2] + red[3]) * (1.0f / Cc);
  float d = v - mean;
  float s2 = d * d;
#pragma unroll
  for (int o = 1; o < 64; o <<= 1) s2 += __shfl_xor(s2, o, 64);
  __syncthreads();
  if ((t & 63) == 0) red[wv] = s2;
  __syncthreads();
  float var = (red[0] + red[1] + red[2] + red[3]) * (1.0f / Cc);
  float r = rsqrtf(var + 1e-5f);
  out[(size_t)row * Cc + t] = __float2bfloat16(d * r * g[t] + bta[t]);
}

// ---------------- bf16 B^T GEMM, 128x128 tile, 16x16x32 MFMA, fused epilogues ----------------
// EPI 0: qkv   -> +bias, scale cols<256 (q), store bf16, stride N
// EPI 1: proj  -> +bias, reverse-roll残 residual add with x, store fp32 (x1)
// EPI 2: fc1   -> +bias, exact GELU, store bf16
// EPI 3: fc2   -> +bias, residual add with aux (x1 in d_out), store fp32
template <int EPI>
__global__ __launch_bounds__(256) void gemm_bt(const __hip_bfloat16* __restrict__ A,
                                               const __hip_bfloat16* __restrict__ BT,
                                               const float* __restrict__ bias,
                                               const float* __restrict__ aux,
                                               void* __restrict__ outv,
                                               int N, int K) {
  const int m0 = blockIdx.x * 128, n0 = blockIdx.y * 128;
  __shared__ __align__(16) __hip_bfloat16 As[128 * 32];
  __shared__ __align__(16) __hip_bfloat16 Bs[128 * 32];
  const int t = threadIdx.x;
  const int wave = t >> 6, lane = t & 63, q = lane >> 4, lr = lane & 15;
  const int wm = (wave >> 1) * 64, wn = (wave & 1) * 64;
  floatx4 acc[4][4] = {};
  for (int k0 = 0; k0 < K; k0 += 32) {
    // stage 128x32 A and B^T tiles: 512 16B chunks each
#pragma unroll
    for (int c = t; c < 512; c += 256) {
      int r = c >> 2, k8 = c & 3;
      ((uint4*)As)[c] = *(const uint4*)(A + (size_t)(m0 + r) * K + k0 + k8 * 8);
      ((uint4*)Bs)[c] = *(const uint4*)(BT + (size_t)(n0 + r) * K + k0 + k8 * 8);
    }
    __syncthreads();
    short8 af[4], bf[4];
#pragma unroll
    for (int i = 0; i < 4; i++) af[i] = *(const short8*)(As + (wm + i * 16 + lr) * 32 + q * 8);
#pragma unroll
    for (int j = 0; j < 4; j++) bf[j] = *(const short8*)(Bs + (wn + j * 16 + lr) * 32 + q * 8);
#pragma unroll
    for (int i = 0; i < 4; i++)
#pragma unroll
      for (int j = 0; j < 4; j++)
        acc[i][j] = __builtin_amdgcn_mfma_f32_16x16x32_bf16(af[i], bf[j], acc[i][j], 0, 0, 0);
    __syncthreads();
  }
  // epilogue: C/D layout row = quad*4+reg, col = lane&15
#pragma unroll
  for (int i = 0; i < 4; i++) {
#pragma unroll
    for (int rg = 0; rg < 4; rg++) {
      int row = m0 + wm + i * 16 + q * 4 + rg;
      int bb = 0, l = 0;
      if (EPI == 1) {
        bb = row / Lc;
        int rl = row - bb * Lc;
        l = rl + Sc; if (l >= Lc) l -= Lc;
      }
#pragma unroll
      for (int j = 0; j < 4; j++) {
        int col = n0 + wn + j * 16 + lr;
        float v = acc[i][j][rg] + bias[col];
        if (EPI == 0) {
          if (col < 256) v *= QSCALE;
          ((__hip_bfloat16*)outv)[(size_t)row * N + col] = __float2bfloat16(v);
        } else if (EPI == 1) {
          size_t o = ((size_t)bb * Lc + l) * Cc + col;
          ((float*)outv)[o] = aux[o] + v;
        } else if (EPI == 2) {
          v = 0.5f * v * (1.0f + erff(v * 0.70710678118654752f));
          ((__hip_bfloat16*)outv)[(size_t)row * N + col] = __float2bfloat16(v);
        } else {
          size_t o = (size_t)row * Cc + col;
          ((float*)outv)[o] = aux[o] + v;
        }
      }
    }
  }
}

// ---------------- fused window attention: 1 wave = 1 (window, head) ----------------
constexpr int PSTR = 72;                 // LDS row stride (elements), 16B-aligned rows, conflict-friendly
constexpr int PSZ = 48 * PSTR;           // P: 48 rows (42 used) x 64 K-cols (42 used)
constexpr int VTSZ = 32 * PSTR;          // V^T: 32 d-rows x 64 j-cols (42 used)

__global__ __launch_bounds__(256) void attn_k(const __hip_bfloat16* __restrict__ qkv,
                                              const float* __restrict__ bias_table,
                                              __hip_bfloat16* __restrict__ o_buf) {
  __shared__ __align__(16) __hip_bfloat16 smem[4 * PSZ + 4 * VTSZ];
  __shared__ float btab[83 * 8];
  const int t = threadIdx.x, wave = t >> 6, lane = t & 63, q = lane >> 4, lr = lane & 15;
  const int win = blockIdx.x >> 1;
  const int h = (blockIdx.x & 1) * 4 + wave;

  // zero P and V^T (pads must be 0), stage bias table
  for (int i = t; i < (4 * PSZ + 4 * VTSZ) / 8; i += 256) ((uint4*)smem)[i] = uint4{0, 0, 0, 0};
  for (int i = t; i < 83 * 8; i += 256) btab[i] = bias_table[i];
  __syncthreads();

  __hip_bfloat16* Pw = smem + wave * PSZ;
  __hip_bfloat16* VTw = smem + 4 * PSZ + wave * VTSZ;
  const __hip_bfloat16* qbase = qkv + (size_t)win * 42 * 768 + h * 32;        // q cols
  const __hip_bfloat16* kbase = qbase + 256;                                   // k cols
  const __hip_bfloat16* vbase = qbase + 512;                                   // v cols

  // stage V^T (d-major so B-fragments read contiguous j)
  for (int i = lane; i < 42 * 32; i += 64) {
    int j = i >> 5, d = i & 31;
    VTw[d * PSTR + j] = vbase[(size_t)j * 768 + d];
  }

  // S = Q K^T : fragments straight from global (contiguous 16B in d)
  short8 qf[3], kf[3];
#pragma unroll
  for (int mt = 0; mt < 3; mt++) {
    int i = mt * 16 + lr; if (i > 41) i = 41;
    qf[mt] = *(const short8*)(qbase + (size_t)i * 768 + q * 8);
  }
#pragma unroll
  for (int nt = 0; nt < 3; nt++) {
    int j = nt * 16 + lr; if (j > 41) j = 41;
    kf[nt] = *(const short8*)(kbase + (size_t)j * 768 + q * 8);
  }
  floatx4 sacc[3][3] = {};
#pragma unroll
  for (int mt = 0; mt < 3; mt++)
#pragma unroll
    for (int nt = 0; nt < 3; nt++)
      sacc[mt][nt] = __builtin_amdgcn_mfma_f32_16x16x32_bf16(qf[mt], kf[nt], sacc[mt][nt], 0, 0, 0);

  // softmax in registers; rows live in (quad, reg), cols in (ntile, lr)
  const bool lastwin = ((win & 63) == 63);
#pragma unroll
  for (int mt = 0; mt < 3; mt++) {
#pragma unroll
    for (int rg = 0; rg < 4; rg++) {
      int row = mt * 16 + q * 4 + rg;
      float sv[3];
      float mx = -1e30f;
#pragma unroll
      for (int nt = 0; nt < 3; nt++) {
        int col = nt * 16 + lr;
        float s = sacc[mt][nt][rg];
        int ri = col - row + 41; ri = ri < 0 ? 0 : (ri > 82 ? 82 : ri);
        s += btab[ri * 8 + h];
        if (lastwin && ((row < 21) != (col < 21))) s -= 100.0f;
        if (col >= 42) s = -1e30f;
        sv[nt] = s;
        mx = fmaxf(mx, s);
      }
#pragma unroll
      for (int o = 1; o < 16; o <<= 1) mx = fmaxf(mx, __shfl_xor(mx, o, 64));
      float sum = 0.0f;
#pragma unroll
      for (int nt = 0; nt < 3; nt++) { float e = __expf(sv[nt] - mx); sv[nt] = e; sum += e; }
#pragma unroll
      for (int o = 1; o < 16; o <<= 1) sum += __shfl_xor(sum, o, 64);
      float inv = 1.0f / sum;
#pragma unroll
      for (int nt = 0; nt < 3; nt++) Pw[row * PSTR + nt * 16 + lr] = __float2bfloat16(sv[nt] * inv);
    }
  }
  __syncthreads();

  // O = P V  (K padded to 64; P pad cols are 0, V^T pad cols are 0)
  floatx4 oacc[3][2] = {};
#pragma unroll
  for (int ks = 0; ks < 2; ks++) {
    short8 pf[3], vf[2];
#pragma unroll
    for (int mt = 0; mt < 3; mt++) pf[mt] = *(const short8*)(Pw + (mt * 16 + lr) * PSTR + ks * 32 + q * 8);
#pragma unroll
    for (int nt = 0; nt < 2; nt++) vf[nt] = *(const short8*)(VTw + (nt * 16 + lr) * PSTR + ks * 32 + q * 8);
#pragma unroll
    for (int mt = 0; mt < 3; mt++)
#pragma unroll
      for (int nt = 0; nt < 2; nt++)
        oacc[mt][nt] = __builtin_amdgcn_mfma_f32_16x16x32_bf16(pf[mt], vf[nt], oacc[mt][nt], 0, 0, 0);
  }
  // store O as (token, h*32+d) bf16
#pragma unroll
  for (int mt = 0; mt < 3; mt++) {
#pragma unroll
    for (int rg = 0; rg < 4; rg++) {
      int row = mt * 16 + q * 4 + rg;
      if (row < 42) {
#pragma unroll
        for (int nt = 0; nt < 2; nt++) {
          int col = nt * 16 + lr;
          o_buf[((size_t)win * 42 + row) * 256 + h * 32 + col] = __float2bfloat16(oacc[mt][nt][rg]);
        }
      }
    }
  }
}

// ---------------- host launch ----------------
extern "C" void kernel_launch(void* const* d_in, const int* in_sizes, int n_in,
                              void* d_out, int out_size, void* d_ws, size_t ws_size,
                              hipStream_t stream) {
  const float* x       = (const float*)d_in[0];
  const float* norm1_g = (const float*)d_in[1];
  const float* norm1_b = (const float*)d_in[2];
  const float* qkv_w   = (const float*)d_in[3];
  const float* qkv_b   = (const float*)d_in[4];
  const float* btab    = (const float*)d_in[5];
  const float* proj_w  = (const float*)d_in[6];
  const float* proj_b  = (const float*)d_in[7];
  const float* norm2_g = (const float*)d_in[8];
  const float* norm2_b = (const float*)d_in[9];
  const float* fc1_w   = (const float*)d_in[10];
  const float* fc1_b   = (const float*)d_in[11];
  const float* fc2_w   = (const float*)d_in[12];
  const float* fc2_b   = (const float*)d_in[13];
  float* out = (float*)d_out;

  char* ws = (char*)d_ws;
  size_t off = 0;
  auto alloc = [&](size_t bytes) { char* p = ws + off; off += (bytes + 255) & ~(size_t)255; return p; };
  __hip_bfloat16* wT_qkv  = (__hip_bfloat16*)alloc((size_t)768 * 256 * 2);
  __hip_bfloat16* wT_proj = (__hip_bfloat16*)alloc((size_t)256 * 256 * 2);
  __hip_bfloat16* wT_fc1  = (__hip_bfloat16*)alloc((size_t)1024 * 256 * 2);
  __hip_bfloat16* wT_fc2  = (__hip_bfloat16*)alloc((size_t)256 * 1024 * 2);
  // 88MB region shared in time by: h (LN1 out) -> o (attn out) -> m (LN2 out)
  __hip_bfloat16* buf88   = (__hip_bfloat16*)alloc((size_t)Mrows * 256 * 2);
  // 352MB region shared in time by: qkv (264MB) -> fc1 activations (352MB)
  __hip_bfloat16* buf352  = (__hip_bfloat16*)alloc((size_t)Mrows * 1024 * 2);

  // 1) weights -> B^T bf16
  transpose_cast_k<<<(256 * 768 + 255) / 256, 256, 0, stream>>>(qkv_w, wT_qkv, 256, 768);
  transpose_cast_k<<<(256 * 256 + 255) / 256, 256, 0, stream>>>(proj_w, wT_proj, 256, 256);
  transpose_cast_k<<<(256 * 1024 + 255) / 256, 256, 0, stream>>>(fc1_w, wT_fc1, 256, 1024);
  transpose_cast_k<<<(1024 * 256 + 255) / 256, 256, 0, stream>>>(fc2_w, wT_fc2, 1024, 256);

  // 2) h = roll(LN1(x), -S) as bf16
  ln_k<<<Mrows, 256, 0, stream>>>(x, norm1_g, norm1_b, buf88, Sc);

  // 3) qkv = h @ qkv_w + b (q pre-scaled), bf16
  gemm_bt<0><<<dim3(Mrows / 128, 768 / 128), 256, 0, stream>>>(buf88, wT_qkv, qkv_b, nullptr, buf352, 768, 256);

  // 4) windowed attention -> o (overwrites buf88; h is dead)
  attn_k<<<(Mrows / Wc) * 2, 256, 0, stream>>>(buf352, btab, buf88);

  // 5) x1 = x + roll(o @ proj_w + b, +S)  -> d_out (fp32)
  gemm_bt<1><<<dim3(Mrows / 128, 256 / 128), 256, 0, stream>>>(buf88, wT_proj, proj_b, x, out, 256, 256);

  // 6) m = LN2(x1) as bf16 (overwrites buf88; o is dead)
  ln_k<<<Mrows, 256, 0, stream>>>(out, norm2_g, norm2_b, buf88, 0);

  // 7) act = gelu(m @ fc1_w + b), bf16 (overwrites buf352; qkv is dead)
  gemm_bt<2><<<dim3(Mrows / 128, 1024 / 128), 256, 0, stream>>>(buf88, wT_fc1, fc1_b, nullptr, buf352, 1024, 256);

  // 8) out = x1 + act @ fc2_w + b  (read-modify-write d_out)
  gemm_bt<3><<<dim3(Mrows / 128, 256 / 128), 256, 0, stream>>>(buf352, wT_fc2, fc2_b, out, out, 256, 1024);

  (void)in_sizes; (void)n_in; (void)out_size; (void)ws_size;
}

// Round 2
// 1183.067 us; speedup vs baseline: 1.2095x; 1.2095x over previous
//
#include <hip/hip_runtime.h>
#include <hip/hip_bf16.h>

typedef short short8 __attribute__((ext_vector_type(8)));
typedef float floatx4 __attribute__((ext_vector_type(4)));

constexpr int Bc = 64, Lc = 2688, Cc = 256, Wc = 42, Sc = 21;
constexpr int Mrows = Bc * Lc;          // 172032
constexpr float QSCALE = 0.17677669529663689f;  // 32^-0.5

#define GLOAD_LDS(g, l) __builtin_amdgcn_global_load_lds( \
    (const __attribute__((address_space(1))) void*)(g),   \
    (__attribute__((address_space(3))) void*)(l), 16, 0, 0)

// ---------------- weight transpose + cast, 32x32 LDS tiles, both sides coalesced ----------------
__global__ __launch_bounds__(256) void transpose_cast_k(const float* __restrict__ w,
                                                        __hip_bfloat16* __restrict__ o,
                                                        int K, int N) {
  __shared__ float tile[32][33];
  int tx = threadIdx.x & 31, ty = threadIdx.x >> 5;    // ty in 0..7
  int n0 = blockIdx.x * 32, k0 = blockIdx.y * 32;
#pragma unroll
  for (int r = 0; r < 32; r += 8)
    tile[ty + r][tx] = w[(size_t)(k0 + ty + r) * N + n0 + tx];
  __syncthreads();
#pragma unroll
  for (int r = 0; r < 32; r += 8)
    o[(size_t)(n0 + ty + r) * K + k0 + tx] = __float2bfloat16(tile[tx][ty + r]);
}

// ---------------- LayerNorm (+ optional cyclic shift), 1 wave = 1 row ----------------
__global__ __launch_bounds__(256) void ln_k(const float* __restrict__ x, const float* __restrict__ g,
                                            const float* __restrict__ bta, __hip_bfloat16* __restrict__ out,
                                            int roll) {
  int row = blockIdx.x * 4 + (threadIdx.x >> 6);
  int lane = threadIdx.x & 63;
  int bb = row / Lc, rl = row - bb * Lc;
  int sl = rl + roll; if (sl >= Lc) sl -= Lc;
  const float4 v = *(const float4*)(x + ((size_t)bb * Lc + sl) * Cc + lane * 4);
  float s = v.x + v.y + v.z + v.w;
#pragma unroll
  for (int o = 1; o < 64; o <<= 1) s += __shfl_xor(s, o, 64);
  float mean = s * (1.0f / Cc);
  float d0 = v.x - mean, d1 = v.y - mean, d2 = v.z - mean, d3 = v.w - mean;
  float s2 = d0 * d0 + d1 * d1 + d2 * d2 + d3 * d3;
#pragma unroll
  for (int o = 1; o < 64; o <<= 1) s2 += __shfl_xor(s2, o, 64);
  float r = rsqrtf(s2 * (1.0f / Cc) + 1e-5f);
  const float4 gg = *(const float4*)(g + lane * 4);
  const float4 bb4 = *(const float4*)(bta + lane * 4);
  __hip_bfloat16 tmp[4];
  tmp[0] = __float2bfloat16(d0 * r * gg.x + bb4.x);
  tmp[1] = __float2bfloat16(d1 * r * gg.y + bb4.y);
  tmp[2] = __float2bfloat16(d2 * r * gg.z + bb4.z);
  tmp[3] = __float2bfloat16(d3 * r * gg.w + bb4.w);
  *(uint2*)(out + (size_t)row * Cc + lane * 4) = *(uint2*)tmp;
}

// ---------------- bf16 B^T GEMM, 128x128 tile, global_load_lds staging (m97 structure) ----------------
// EPI 0: qkv   -> +bias, scale cols<256 (q), store bf16
// EPI 1: proj  -> +bias, reverse-roll residual add with x, store fp32 (x1)
// EPI 2: fc1   -> +bias, exact GELU, store bf16
// EPI 3: fc2   -> +bias, residual add with aux, store fp32
template <int EPI>
__global__ __launch_bounds__(256) void gemm_bt(const __hip_bfloat16* __restrict__ A,
                                               const __hip_bfloat16* __restrict__ BT,
                                               const float* __restrict__ bias,
                                               const float* __restrict__ aux,
                                               void* __restrict__ outv,
                                               int N, int K) {
  const int n0 = blockIdx.x * 128, m0 = blockIdx.y * 128;   // n fastest: A-tile reused across N-slices
  __shared__ __align__(16) __hip_bfloat16 As[128 * 32];
  __shared__ __align__(16) __hip_bfloat16 Bs[128 * 32];
  const int t = threadIdx.x;
  const int wave = t >> 6, lane = t & 63, q = lane >> 4, lr = lane & 15;
  const int wm = (wave >> 1) * 64, wn = (wave & 1) * 64;

  // staging: chunk c = t (+256) -> (row c>>2, k-elems (c&3)*8), LDS position c*16B
  const int srow = t >> 2, sk = (t & 3) * 8;
  const __hip_bfloat16* gA0 = A + (size_t)(m0 + srow) * K + sk;
  const __hip_bfloat16* gA1 = gA0 + (size_t)64 * K;
  const __hip_bfloat16* gB0 = BT + (size_t)(n0 + srow) * K + sk;
  const __hip_bfloat16* gB1 = gB0 + (size_t)64 * K;
  __hip_bfloat16* lA0 = As + wave * 512;          // wave-uniform base; lane adds lane*16B
  __hip_bfloat16* lA1 = As + 2048 + wave * 512;
  __hip_bfloat16* lB0 = Bs + wave * 512;
  __hip_bfloat16* lB1 = Bs + 2048 + wave * 512;

  floatx4 acc[4][4] = {};
  for (int k0 = 0; k0 < K; k0 += 32) {
    GLOAD_LDS(gA0 + k0, lA0);
    GLOAD_LDS(gA1 + k0, lA1);
    GLOAD_LDS(gB0 + k0, lB0);
    GLOAD_LDS(gB1 + k0, lB1);
    __syncthreads();
    short8 af[4], bf[4];
#pragma unroll
    for (int i = 0; i < 4; i++) af[i] = *(const short8*)(As + (wm + i * 16 + lr) * 32 + q * 8);
#pragma unroll
    for (int j = 0; j < 4; j++) bf[j] = *(const short8*)(Bs + (wn + j * 16 + lr) * 32 + q * 8);
#pragma unroll
    for (int i = 0; i < 4; i++)
#pragma unroll
      for (int j = 0; j < 4; j++)
        acc[i][j] = __builtin_amdgcn_mfma_f32_16x16x32_bf16(af[i], bf[j], acc[i][j], 0, 0, 0);
    __syncthreads();
  }
  // epilogue: C/D layout row = quad*4+reg, col = lane&15
#pragma unroll
  for (int i = 0; i < 4; i++) {
#pragma unroll
    for (int rg = 0; rg < 4; rg++) {
      int row = m0 + wm + i * 16 + q * 4 + rg;
      int bb = 0, l = 0;
      if (EPI == 1) {
        bb = row / Lc;
        int rl = row - bb * Lc;
        l = rl + Sc; if (l >= Lc) l -= Lc;
      }
#pragma unroll
      for (int j = 0; j < 4; j++) {
        int col = n0 + wn + j * 16 + lr;
        float v = acc[i][j][rg] + bias[col];
        if (EPI == 0) {
          if (col < 256) v *= QSCALE;
          ((__hip_bfloat16*)outv)[(size_t)row * N + col] = __float2bfloat16(v);
        } else if (EPI == 1) {
          size_t o = ((size_t)bb * Lc + l) * Cc + col;
          ((float*)outv)[o] = aux[o] + v;
        } else if (EPI == 2) {
          v = 0.5f * v * (1.0f + erff(v * 0.70710678118654752f));
          ((__hip_bfloat16*)outv)[(size_t)row * N + col] = __float2bfloat16(v);
        } else {
          size_t o = (size_t)row * Cc + col;
          ((float*)outv)[o] = aux[o] + v;
        }
      }
    }
  }
}

// ---------------- fused window attention: 1 wave = 1 (window, head) ----------------
constexpr int PSTR = 72;                 // LDS row stride (elements)
constexpr int PSZ = 48 * PSTR;           // P: 48 rows x 64 K-cols (42 used)
constexpr int VTSZ = 32 * PSTR;          // V^T: 32 d-rows x 64 j-cols (42 used)

__global__ __launch_bounds__(256) void attn_k(const __hip_bfloat16* __restrict__ qkv,
                                              const float* __restrict__ bias_table,
                                              __hip_bfloat16* __restrict__ o_buf) {
  __shared__ __align__(16) __hip_bfloat16 smem[4 * PSZ + 4 * VTSZ];
  __shared__ float btab[83 * 8];
  const int t = threadIdx.x, wave = t >> 6, lane = t & 63, q = lane >> 4, lr = lane & 15;
  const int win = blockIdx.x >> 1;
  const int h = (blockIdx.x & 1) * 4 + wave;

  for (int i = t; i < (4 * PSZ + 4 * VTSZ) / 8; i += 256) ((uint4*)smem)[i] = uint4{0, 0, 0, 0};
  for (int i = t; i < 83 * 8; i += 256) btab[i] = bias_table[i];
  __syncthreads();

  __hip_bfloat16* Pw = smem + wave * PSZ;
  __hip_bfloat16* VTw = smem + 4 * PSZ + wave * VTSZ;
  const __hip_bfloat16* qbase = qkv + (size_t)win * 42 * 768 + h * 32;
  const __hip_bfloat16* kbase = qbase + 256;
  const __hip_bfloat16* vbase = qbase + 512;

  // stage V^T: 16B coalesced global loads, scalar LDS scatter (transpose)
  for (int c = lane; c < 42 * 4; c += 64) {      // 168 chunks of 8 bf16
    int j = c >> 2, d0 = (c & 3) * 8;
    short8 vv = *(const short8*)(vbase + (size_t)j * 768 + d0);
#pragma unroll
    for (int e = 0; e < 8; e++) ((short*)VTw)[(d0 + e) * PSTR + j] = vv[e];
  }

  // S = Q K^T : fragments straight from global (contiguous 16B in d)
  short8 qf[3], kf[3];
#pragma unroll
  for (int mt = 0; mt < 3; mt++) {
    int i = mt * 16 + lr; if (i > 41) i = 41;
    qf[mt] = *(const short8*)(qbase + (size_t)i * 768 + q * 8);
  }
#pragma unroll
  for (int nt = 0; nt < 3; nt++) {
    int j = nt * 16 + lr; if (j > 41) j = 41;
    kf[nt] = *(const short8*)(kbase + (size_t)j * 768 + q * 8);
  }
  floatx4 sacc[3][3] = {};
#pragma unroll
  for (int mt = 0; mt < 3; mt++)
#pragma unroll
    for (int nt = 0; nt < 3; nt++)
      sacc[mt][nt] = __builtin_amdgcn_mfma_f32_16x16x32_bf16(qf[mt], kf[nt], sacc[mt][nt], 0, 0, 0);

  const bool lastwin = ((win & 63) == 63);
#pragma unroll
  for (int mt = 0; mt < 3; mt++) {
#pragma unroll
    for (int rg = 0; rg < 4; rg++) {
      int row = mt * 16 + q * 4 + rg;
      float sv[3];
      float mx = -1e30f;
#pragma unroll
      for (int nt = 0; nt < 3; nt++) {
        int col = nt * 16 + lr;
        float s = sacc[mt][nt][rg];
        int ri = col - row + 41; ri = ri < 0 ? 0 : (ri > 82 ? 82 : ri);
        s += btab[ri * 8 + h];
        if (lastwin && ((row < 21) != (col < 21))) s -= 100.0f;
        if (col >= 42) s = -1e30f;
        sv[nt] = s;
        mx = fmaxf(mx, s);
      }
#pragma unroll
      for (int o = 1; o < 16; o <<= 1) mx = fmaxf(mx, __shfl_xor(mx, o, 64));
      float sum = 0.0f;
#pragma unroll
      for (int nt = 0; nt < 3; nt++) { float e = __expf(sv[nt] - mx); sv[nt] = e; sum += e; }
#pragma unroll
      for (int o = 1; o < 16; o <<= 1) sum += __shfl_xor(sum, o, 64);
      float inv = 1.0f / sum;
#pragma unroll
      for (int nt = 0; nt < 3; nt++) Pw[row * PSTR + nt * 16 + lr] = __float2bfloat16(sv[nt] * inv);
    }
  }
  __syncthreads();

  floatx4 oacc[3][2] = {};
#pragma unroll
  for (int ks = 0; ks < 2; ks++) {
    short8 pf[3], vf[2];
#pragma unroll
    for (int mt = 0; mt < 3; mt++) pf[mt] = *(const short8*)(Pw + (mt * 16 + lr) * PSTR + ks * 32 + q * 8);
#pragma unroll
    for (int nt = 0; nt < 2; nt++) vf[nt] = *(const short8*)(VTw + (nt * 16 + lr) * PSTR + ks * 32 + q * 8);
#pragma unroll
    for (int mt = 0; mt < 3; mt++)
#pragma unroll
      for (int nt = 0; nt < 2; nt++)
        oacc[mt][nt] = __builtin_amdgcn_mfma_f32_16x16x32_bf16(pf[mt], vf[nt], oacc[mt][nt], 0, 0, 0);
  }
#pragma unroll
  for (int mt = 0; mt < 3; mt++) {
#pragma unroll
    for (int rg = 0; rg < 4; rg++) {
      int row = mt * 16 + q * 4 + rg;
      if (row < 42) {
#pragma unroll
        for (int nt = 0; nt < 2; nt++) {
          int col = nt * 16 + lr;
          o_buf[((size_t)win * 42 + row) * 256 + h * 32 + col] = __float2bfloat16(oacc[mt][nt][rg]);
        }
      }
    }
  }
}

// ---------------- host launch ----------------
extern "C" void kernel_launch(void* const* d_in, const int* in_sizes, int n_in,
                              void* d_out, int out_size, void* d_ws, size_t ws_size,
                              hipStream_t stream) {
  const float* x       = (const float*)d_in[0];
  const float* norm1_g = (const float*)d_in[1];
  const float* norm1_b = (const float*)d_in[2];
  const float* qkv_w   = (const float*)d_in[3];
  const float* qkv_b   = (const float*)d_in[4];
  const float* btab    = (const float*)d_in[5];
  const float* proj_w  = (const float*)d_in[6];
  const float* proj_b  = (const float*)d_in[7];
  const float* norm2_g = (const float*)d_in[8];
  const float* norm2_b = (const float*)d_in[9];
  const float* fc1_w   = (const float*)d_in[10];
  const float* fc1_b   = (const float*)d_in[11];
  const float* fc2_w   = (const float*)d_in[12];
  const float* fc2_b   = (const float*)d_in[13];
  float* out = (float*)d_out;

  char* ws = (char*)d_ws;
  size_t off = 0;
  auto alloc = [&](size_t bytes) { char* p = ws + off; off += (bytes + 255) & ~(size_t)255; return p; };
  __hip_bfloat16* wT_qkv  = (__hip_bfloat16*)alloc((size_t)768 * 256 * 2);
  __hip_bfloat16* wT_proj = (__hip_bfloat16*)alloc((size_t)256 * 256 * 2);
  __hip_bfloat16* wT_fc1  = (__hip_bfloat16*)alloc((size_t)1024 * 256 * 2);
  __hip_bfloat16* wT_fc2  = (__hip_bfloat16*)alloc((size_t)256 * 1024 * 2);
  __hip_bfloat16* buf88   = (__hip_bfloat16*)alloc((size_t)Mrows * 256 * 2);   // h -> o -> m
  __hip_bfloat16* buf352  = (__hip_bfloat16*)alloc((size_t)Mrows * 1024 * 2);  // qkv -> fc1 act

  // 1) weights -> B^T bf16 (coalesced tiles)
  transpose_cast_k<<<dim3(768 / 32, 256 / 32), 256, 0, stream>>>(qkv_w, wT_qkv, 256, 768);
  transpose_cast_k<<<dim3(256 / 32, 256 / 32), 256, 0, stream>>>(proj_w, wT_proj, 256, 256);
  transpose_cast_k<<<dim3(1024 / 32, 256 / 32), 256, 0, stream>>>(fc1_w, wT_fc1, 256, 1024);
  transpose_cast_k<<<dim3(256 / 32, 1024 / 32), 256, 0, stream>>>(fc2_w, wT_fc2, 1024, 256);

  // 2) h = roll(LN1(x), -S) as bf16
  ln_k<<<Mrows / 4, 256, 0, stream>>>(x, norm1_g, norm1_b, buf88, Sc);

  // 3) qkv = h @ qkv_w + b (q pre-scaled), bf16
  gemm_bt<0><<<dim3(768 / 128, Mrows / 128), 256, 0, stream>>>(buf88, wT_qkv, qkv_b, nullptr, buf352, 768, 256);

  // 4) windowed attention -> o
  attn_k<<<(Mrows / Wc) * 2, 256, 0, stream>>>(buf352, btab, buf88);

  // 5) x1 = x + roll(o @ proj_w + b, +S)  -> d_out (fp32)
  gemm_bt<1><<<dim3(256 / 128, Mrows / 128), 256, 0, stream>>>(buf88, wT_proj, proj_b, x, out, 256, 256);

  // 6) m = LN2(x1) as bf16
  ln_k<<<Mrows / 4, 256, 0, stream>>>(out, norm2_g, norm2_b, buf88, 0);

  // 7) act = gelu(m @ fc1_w + b), bf16
  gemm_bt<2><<<dim3(1024 / 128, Mrows / 128), 256, 0, stream>>>(buf88, wT_fc1, fc1_b, nullptr, buf352, 1024, 256);

  // 8) out = x1 + act @ fc2_w + b
  gemm_bt<3><<<dim3(256 / 128, Mrows / 128), 256, 0, stream>>>(buf352, wT_fc2, fc2_b, out, out, 256, 1024);

  (void)in_sizes; (void)n_in; (void)out_size; (void)ws_size;
}